// Round 1
// baseline (1975.785 us; speedup 1.0000x reference)
//
#include <hip/hip_runtime.h>

typedef unsigned short u16;
typedef unsigned int u32;
using u16x4 = __attribute__((ext_vector_type(4))) u16;
using u16x8 = __attribute__((ext_vector_type(8))) u16;
using bf16x8 = __attribute__((ext_vector_type(8))) __bf16;
using f32x4 = __attribute__((ext_vector_type(4))) float;

#define B_ 8
#define T_ 2048
#define C_ 768
#define E_ 8
#define K_ 2
#define H_ 3072
#define CAP_ 640
#define M_ (B_ * CAP_) /* 5120 rows per expert */

__device__ __forceinline__ u16 f2bf(float x) {
  u32 u = __float_as_uint(x);
  u32 r = (u + 0x7FFFu + ((u >> 16) & 1u)) >> 16;  // RNE
  return (u16)r;
}
__device__ __forceinline__ float bf2f(u16 v) { return __uint_as_float(((u32)v) << 16); }

__device__ __forceinline__ void gl_lds16(const u16* g, u16* l) {
  __builtin_amdgcn_global_load_lds((const __attribute__((address_space(1))) u32*)g,
                                   (__attribute__((address_space(3))) u32*)l, 16, 0, 0);
}
__device__ __forceinline__ bf16x8 ldfrag(const u16* p) {
  return __builtin_bit_cast(bf16x8, *(const u16x8*)p);
}

// ---------- weight fp32 -> bf16 transpose:  in [E][R][Cc] -> out [E][Cc][R] ----------
__global__ void wconv_transpose(const float* __restrict__ in, u16* __restrict__ out,
                                int R, int Cc) {
  __shared__ float tile[32][33];
  const float* inE = in + (size_t)blockIdx.z * R * Cc;
  u16* outE = out + (size_t)blockIdx.z * R * Cc;
  int tx = threadIdx.x & 31, ty = threadIdx.x >> 5;  // 32 x 8
  int r0 = blockIdx.y * 32, c0 = blockIdx.x * 32;
#pragma unroll
  for (int j = 0; j < 4; j++)
    tile[ty + j * 8][tx] = inE[(size_t)(r0 + ty + j * 8) * Cc + (c0 + tx)];
  __syncthreads();
#pragma unroll
  for (int j = 0; j < 4; j++)
    outE[(size_t)(c0 + ty + j * 8) * R + (r0 + tx)] = f2bf(tile[tx][ty + j * 8]);
}

// ---------- router: logits, softmax, top-2 (fp64 accumulate; tie -> lower index) ----------
__global__ void router_kernel(const float* __restrict__ x, const float* __restrict__ wr,
                              const float* __restrict__ br, float* __restrict__ tkp,
                              int* __restrict__ tki) {
  int bt = (blockIdx.x << 2) | (threadIdx.x >> 6);  // token index b*T+t
  int lane = threadIdx.x & 63;
  const float* xr = x + (size_t)bt * C_;
  double acc[E_];
#pragma unroll
  for (int e = 0; e < E_; e++) acc[e] = 0.0;
#pragma unroll
  for (int i = 0; i < C_ / 64; i++) {
    int c = lane + i * 64;
    float xv = xr[c];
    const float* w = wr + c * E_;
#pragma unroll
    for (int e = 0; e < E_; e++) acc[e] += (double)xv * (double)w[e];
  }
#pragma unroll
  for (int off = 32; off > 0; off >>= 1) {
#pragma unroll
    for (int e = 0; e < E_; e++) acc[e] += __shfl_xor(acc[e], off);
  }
  if (lane == 0) {
    double lg[E_];
#pragma unroll
    for (int e = 0; e < E_; e++) lg[e] = acc[e] + (double)br[e];
    int i0 = 0;
#pragma unroll
    for (int e = 1; e < E_; e++) if (lg[e] > lg[i0]) i0 = e;
    int i1 = (i0 == 0) ? 1 : 0;
#pragma unroll
    for (int e = 0; e < E_; e++) if (e != i0 && lg[e] > lg[i1]) i1 = e;
    double mx = lg[i0], s = 0.0, pv[E_];
#pragma unroll
    for (int e = 0; e < E_; e++) { pv[e] = exp(lg[e] - mx); s += pv[e]; }
    tkp[bt * 2 + 0] = (float)(pv[i0] / s);
    tkp[bt * 2 + 1] = (float)(pv[i1] / s);
    tki[bt * 2 + 0] = i0;
    tki[bt * 2 + 1] = i1;
  }
}

// ---------- slot positions: sequential k-major scan, one thread per (b, e) ----------
__global__ void pos_kernel(const int* __restrict__ tki, int* __restrict__ pos) {
  int tid = threadIdx.x;  // 64 threads
  int b = tid >> 3, e = tid & 7;
  const int* tib = tki + (size_t)b * T_ * 2;
  int* pb = pos + (size_t)b * T_ * 2;
  int cnt = 0;
  for (int i = 0; i < K_ * T_; i++) {
    int k = i >> 11, t = i & (T_ - 1);  // k-major order (k*T + t)
    int idx = t * 2 + k;
    if (tib[idx] == e) { pb[idx] = cnt; cnt++; }
  }
}

// ---------- dispatch: x row -> bf16 expert buffer [E][M_][C_] ----------
__global__ void dispatch_kernel(const float* __restrict__ x, const int* __restrict__ tki,
                                const int* __restrict__ pos, u16* __restrict__ Xd) {
  int gw = (blockIdx.x << 2) | (threadIdx.x >> 6);  // (b*T+t)*2 + k
  int lane = threadIdx.x & 63;
  int bt = gw >> 1;
  int b = bt >> 11;
  int e = tki[gw];
  int p = pos[gw];
  if (p >= CAP_) return;  // capacity drop
  const f32x4* src = (const f32x4*)(x + (size_t)bt * C_);
  u16* dst = Xd + ((size_t)e * M_ + (size_t)b * CAP_ + p) * C_;
#pragma unroll
  for (int i = 0; i < 3; i++) {
    f32x4 v = src[lane + i * 64];
    u16x4 o;
    o.x = f2bf(v.x); o.y = f2bf(v.y); o.z = f2bf(v.z); o.w = f2bf(v.w);
    *(u16x4*)(dst + (size_t)(lane + i * 64) * 4) = o;
  }
}

// ---------- GEMM1: S = silu((X@Wfc+bfc)*(X@Wg+bg)), dual-B 128x128 tile ----------
__global__ __launch_bounds__(256, 2) void gemm_fc_gate(
    const u16* __restrict__ Xd, const u16* __restrict__ WfcT, const u16* __restrict__ WgT,
    const float* __restrict__ bfc, const float* __restrict__ bg, u16* __restrict__ S,
    int e_base) {
  __shared__ __align__(16) u16 Alds[128 * 32];
  __shared__ __align__(16) u16 B1lds[128 * 32];
  __shared__ __align__(16) u16 B2lds[128 * 32];
  int bid = blockIdx.x;
  int e = e_base + bid / (40 * 24);
  int t = bid % (40 * 24);
  int tm = t / 24, tn = t % 24;
  int tid = threadIdx.x;
  int lane = tid & 63, wv = tid >> 6;
  int wm = wv & 1, wn = wv >> 1;
  int lr = lane & 15, quad = lane >> 4;

  const u16* XdE = Xd + (size_t)e * M_ * C_;
  const u16* B1E = WfcT + (size_t)e * H_ * C_;  // [H][C] = [N][K]
  const u16* B2E = WgT + (size_t)e * H_ * C_;

  int rhalf = tid >> 2;  // 0..63
  int chunk = tid & 3;
  const u16* gA0 = XdE + (size_t)(tm * 128 + rhalf) * C_ + chunk * 8;
  const u16* gA1 = gA0 + 64 * C_;
  const u16* gB10 = B1E + (size_t)(tn * 128 + rhalf) * C_ + chunk * 8;
  const u16* gB11 = gB10 + 64 * C_;
  const u16* gB20 = B2E + (size_t)(tn * 128 + rhalf) * C_ + chunk * 8;
  const u16* gB21 = gB20 + 64 * C_;
  u16* lA0 = Alds + (wv * 16) * 32;
  u16* lA1 = Alds + (64 + wv * 16) * 32;
  u16* lB10 = B1lds + (wv * 16) * 32;
  u16* lB11 = B1lds + (64 + wv * 16) * 32;
  u16* lB20 = B2lds + (wv * 16) * 32;
  u16* lB21 = B2lds + (64 + wv * 16) * 32;

  f32x4 acc1[4][4], acc2[4][4];
#pragma unroll
  for (int i = 0; i < 4; i++)
#pragma unroll
    for (int j = 0; j < 4; j++) {
      acc1[i][j] = (f32x4){0.f, 0.f, 0.f, 0.f};
      acc2[i][j] = (f32x4){0.f, 0.f, 0.f, 0.f};
    }

  for (int kt = 0; kt < C_ / 32; kt++) {
    int ko = kt * 32;
    __syncthreads();
    gl_lds16(gA0 + ko, lA0);
    gl_lds16(gA1 + ko, lA1);
    gl_lds16(gB10 + ko, lB10);
    gl_lds16(gB11 + ko, lB11);
    gl_lds16(gB20 + ko, lB20);
    gl_lds16(gB21 + ko, lB21);
    __syncthreads();
    bf16x8 af[4], b1f[4], b2f[4];
#pragma unroll
    for (int i = 0; i < 4; i++) {
      af[i] = ldfrag(Alds + (wm * 64 + i * 16 + lr) * 32 + quad * 8);
      b1f[i] = ldfrag(B1lds + (wn * 64 + i * 16 + lr) * 32 + quad * 8);
      b2f[i] = ldfrag(B2lds + (wn * 64 + i * 16 + lr) * 32 + quad * 8);
    }
#pragma unroll
    for (int i = 0; i < 4; i++)
#pragma unroll
      for (int j = 0; j < 4; j++) {
        acc1[i][j] = __builtin_amdgcn_mfma_f32_16x16x32_bf16(af[i], b1f[j], acc1[i][j], 0, 0, 0);
        acc2[i][j] = __builtin_amdgcn_mfma_f32_16x16x32_bf16(af[i], b2f[j], acc2[i][j], 0, 0, 0);
      }
  }

  u16* Se = S + (size_t)(e - e_base) * M_ * H_;
  const float* bfcE = bfc + (size_t)e * H_;
  const float* bgE = bg + (size_t)e * H_;
  int col0 = tn * 128 + wn * 64 + lr;
  int row0 = tm * 128 + wm * 64 + quad * 4;
#pragma unroll
  for (int j = 0; j < 4; j++) {
    int col = col0 + j * 16;
    float bf_ = bfcE[col], bg_ = bgE[col];
#pragma unroll
    for (int i = 0; i < 4; i++) {
      int row = row0 + i * 16;
#pragma unroll
      for (int r = 0; r < 4; r++) {
        float h = acc1[i][j][r] + bf_;
        float g = acc2[i][j][r] + bg_;
        float z = h * g;
        float sv = z / (1.f + __expf(-z));  // silu
        Se[(size_t)(row + r) * H_ + col] = f2bf(sv);
      }
    }
  }
}

// ---------- GEMM2: O = S @ Wproj + bproj ----------
__global__ __launch_bounds__(256, 2) void gemm_proj(
    const u16* __restrict__ S, const u16* __restrict__ WpT, const float* __restrict__ bp,
    u16* __restrict__ O, int e_base) {
  __shared__ __align__(16) u16 Alds[128 * 32];
  __shared__ __align__(16) u16 Blds[128 * 32];
  int bid = blockIdx.x;
  int eg = bid / (40 * 6);
  int e = e_base + eg;
  int t = bid % (40 * 6);
  int tm = t / 6, tn = t % 6;
  int tid = threadIdx.x;
  int lane = tid & 63, wv = tid >> 6;
  int wm = wv & 1, wn = wv >> 1;
  int lr = lane & 15, quad = lane >> 4;

  const u16* SE = S + (size_t)eg * M_ * H_;
  const u16* BE = WpT + (size_t)e * C_ * H_;  // [C][H] = [N][K]

  int rhalf = tid >> 2;
  int chunk = tid & 3;
  const u16* gA0 = SE + (size_t)(tm * 128 + rhalf) * H_ + chunk * 8;
  const u16* gA1 = gA0 + 64 * H_;
  const u16* gB0 = BE + (size_t)(tn * 128 + rhalf) * H_ + chunk * 8;
  const u16* gB1 = gB0 + 64 * H_;
  u16* lA0 = Alds + (wv * 16) * 32;
  u16* lA1 = Alds + (64 + wv * 16) * 32;
  u16* lB0 = Blds + (wv * 16) * 32;
  u16* lB1 = Blds + (64 + wv * 16) * 32;

  f32x4 acc[4][4];
#pragma unroll
  for (int i = 0; i < 4; i++)
#pragma unroll
    for (int j = 0; j < 4; j++) acc[i][j] = (f32x4){0.f, 0.f, 0.f, 0.f};

  for (int kt = 0; kt < H_ / 32; kt++) {
    int ko = kt * 32;
    __syncthreads();
    gl_lds16(gA0 + ko, lA0);
    gl_lds16(gA1 + ko, lA1);
    gl_lds16(gB0 + ko, lB0);
    gl_lds16(gB1 + ko, lB1);
    __syncthreads();
    bf16x8 af[4], bf[4];
#pragma unroll
    for (int i = 0; i < 4; i++) {
      af[i] = ldfrag(Alds + (wm * 64 + i * 16 + lr) * 32 + quad * 8);
      bf[i] = ldfrag(Blds + (wn * 64 + i * 16 + lr) * 32 + quad * 8);
    }
#pragma unroll
    for (int i = 0; i < 4; i++)
#pragma unroll
      for (int j = 0; j < 4; j++)
        acc[i][j] = __builtin_amdgcn_mfma_f32_16x16x32_bf16(af[i], bf[j], acc[i][j], 0, 0, 0);
  }

  u16* Oe = O + (size_t)e * M_ * C_;
  const float* bpE = bp + (size_t)e * C_;
  int col0 = tn * 128 + wn * 64 + lr;
  int row0 = tm * 128 + wm * 64 + quad * 4;
#pragma unroll
  for (int j = 0; j < 4; j++) {
    int col = col0 + j * 16;
    float bb = bpE[col];
#pragma unroll
    for (int i = 0; i < 4; i++) {
      int row = row0 + i * 16;
#pragma unroll
      for (int r = 0; r < 4; r++)
        Oe[(size_t)(row + r) * C_ + col] = f2bf(acc[i][j][r] + bb);
    }
  }
}

// ---------- combine: out = p0*O[e0,slot0] + p1*O[e1,slot1]  (clamp slot, jax gather) ----------
__global__ void combine_kernel(const u16* __restrict__ O, const float* __restrict__ tkp,
                               const int* __restrict__ tki, const int* __restrict__ pos,
                               float* __restrict__ out) {
  int bt = (blockIdx.x << 2) | (threadIdx.x >> 6);
  int lane = threadIdx.x & 63;
  int b = bt >> 11;
  int e0 = tki[bt * 2], e1 = tki[bt * 2 + 1];
  int p0 = pos[bt * 2], p1 = pos[bt * 2 + 1];
  p0 = p0 < CAP_ ? p0 : CAP_ - 1;  // jax clip-gather semantics
  p1 = p1 < CAP_ ? p1 : CAP_ - 1;
  float w0 = tkp[bt * 2], w1 = tkp[bt * 2 + 1];
  const u16* r0 = O + ((size_t)e0 * M_ + (size_t)b * CAP_ + p0) * C_;
  const u16* r1 = O + ((size_t)e1 * M_ + (size_t)b * CAP_ + p1) * C_;
  float* orow = out + (size_t)bt * C_;
#pragma unroll
  for (int i = 0; i < 3; i++) {
    int c = (lane + i * 64) * 4;
    u16x4 a0 = *(const u16x4*)(r0 + c);
    u16x4 a1 = *(const u16x4*)(r1 + c);
    f32x4 v;
    v.x = w0 * bf2f(a0.x) + w1 * bf2f(a1.x);
    v.y = w0 * bf2f(a0.y) + w1 * bf2f(a1.y);
    v.z = w0 * bf2f(a0.z) + w1 * bf2f(a1.z);
    v.w = w0 * bf2f(a0.w) + w1 * bf2f(a1.w);
    *(f32x4*)(orow + c) = v;
  }
}

extern "C" void kernel_launch(void* const* d_in, const int* in_sizes, int n_in,
                              void* d_out, int out_size, void* d_ws, size_t ws_size,
                              hipStream_t stream) {
  (void)in_sizes; (void)n_in; (void)out_size;
  const float* x = (const float*)d_in[0];
  const float* w_router = (const float*)d_in[1];
  const float* b_router = (const float*)d_in[2];
  const float* w_c_fc = (const float*)d_in[3];
  const float* b_c_fc = (const float*)d_in[4];
  const float* w_gate = (const float*)d_in[5];
  const float* b_gate = (const float*)d_in[6];
  const float* w_c_proj = (const float*)d_in[7];
  const float* b_c_proj = (const float*)d_in[8];
  float* out = (float*)d_out;

  char* p = (char*)d_ws;
  auto alloc = [&](size_t n) { char* r = p; p += (n + 255) & ~(size_t)255; return r; };
  const size_t WN = (size_t)E_ * C_ * H_;
  u16* WfcT = (u16*)alloc(WN * 2);
  u16* WgT = (u16*)alloc(WN * 2);
  u16* WpT = (u16*)alloc(WN * 2);
  u16* Xd = (u16*)alloc((size_t)E_ * M_ * C_ * 2);
  u16* O = (u16*)alloc((size_t)E_ * M_ * C_ * 2);
  float* tkp = (float*)alloc((size_t)B_ * T_ * 2 * 4);
  int* tki = (int*)alloc((size_t)B_ * T_ * 2 * 4);
  int* pos = (int*)alloc((size_t)B_ * T_ * 2 * 4);
  size_t fixed = (size_t)(p - (char*)d_ws);
  const size_t sbytes = (size_t)M_ * H_ * 2;  // per-expert S (31.5 MB)
  int g = 1;
  if (ws_size >= fixed + 8 * sbytes) g = 8;
  else if (ws_size >= fixed + 4 * sbytes) g = 4;
  else if (ws_size >= fixed + 2 * sbytes) g = 2;
  u16* S = (u16*)alloc((size_t)g * sbytes);

  dim3 blk(256);
  // weights -> bf16, transposed to [N][K]
  wconv_transpose<<<dim3(H_ / 32, C_ / 32, E_), blk, 0, stream>>>(w_c_fc, WfcT, C_, H_);
  wconv_transpose<<<dim3(H_ / 32, C_ / 32, E_), blk, 0, stream>>>(w_gate, WgT, C_, H_);
  wconv_transpose<<<dim3(C_ / 32, H_ / 32, E_), blk, 0, stream>>>(w_c_proj, WpT, H_, C_);

  router_kernel<<<dim3(B_ * T_ / 4), blk, 0, stream>>>(x, w_router, b_router, tkp, tki);
  pos_kernel<<<dim3(1), dim3(64), 0, stream>>>(tki, pos);
  dispatch_kernel<<<dim3(B_ * T_ * K_ / 4), blk, 0, stream>>>(x, tki, pos, Xd);

  for (int e0 = 0; e0 < E_; e0 += g) {
    gemm_fc_gate<<<dim3(g * 40 * 24), blk, 0, stream>>>(Xd, WfcT, WgT, b_c_fc, b_gate, S, e0);
    gemm_proj<<<dim3(g * 40 * 6), blk, 0, stream>>>(S, WpT, b_c_proj, O, e0);
  }

  combine_kernel<<<dim3(B_ * T_ / 4), blk, 0, stream>>>(O, tkp, tki, pos, out);
}

// Round 2
// 1402.200 us; speedup vs baseline: 1.4091x; 1.4091x over previous
//
#include <hip/hip_runtime.h>

typedef unsigned short u16;
typedef unsigned int u32;
using u16x4 = __attribute__((ext_vector_type(4))) u16;
using u16x8 = __attribute__((ext_vector_type(8))) u16;
using bf16x8 = __attribute__((ext_vector_type(8))) __bf16;
using f32x4 = __attribute__((ext_vector_type(4))) float;

#define B_ 8
#define T_ 2048
#define C_ 768
#define E_ 8
#define K_ 2
#define H_ 3072
#define CAP_ 640
#define M_ (B_ * CAP_) /* 5120 rows per expert */

__device__ __forceinline__ u16 f2bf(float x) {
  u32 u = __float_as_uint(x);
  u32 r = (u + 0x7FFFu + ((u >> 16) & 1u)) >> 16;  // RNE
  return (u16)r;
}
__device__ __forceinline__ float bf2f(u16 v) { return __uint_as_float(((u32)v) << 16); }

__device__ __forceinline__ void gl_lds16(const u16* g, u16* l) {
  __builtin_amdgcn_global_load_lds((const __attribute__((address_space(1))) u32*)g,
                                   (__attribute__((address_space(3))) u32*)l, 16, 0, 0);
}
__device__ __forceinline__ bf16x8 ldfrag(const u16* p) {
  return __builtin_bit_cast(bf16x8, *(const u16x8*)p);
}

// ---------- weight fp32 -> bf16 transpose:  in [E][R][Cc] -> out [E][Cc][R] ----------
__global__ void wconv_transpose(const float* __restrict__ in, u16* __restrict__ out,
                                int R, int Cc) {
  __shared__ float tile[32][33];
  const float* inE = in + (size_t)blockIdx.z * R * Cc;
  u16* outE = out + (size_t)blockIdx.z * R * Cc;
  int tx = threadIdx.x & 31, ty = threadIdx.x >> 5;  // 32 x 8
  int r0 = blockIdx.y * 32, c0 = blockIdx.x * 32;
#pragma unroll
  for (int j = 0; j < 4; j++)
    tile[ty + j * 8][tx] = inE[(size_t)(r0 + ty + j * 8) * Cc + (c0 + tx)];
  __syncthreads();
#pragma unroll
  for (int j = 0; j < 4; j++)
    outE[(size_t)(c0 + ty + j * 8) * R + (r0 + tx)] = f2bf(tile[tx][ty + j * 8]);
}

// ---------- router: logits, softmax, top-2 (fp64 accumulate; tie -> lower index) ----------
__global__ void router_kernel(const float* __restrict__ x, const float* __restrict__ wr,
                              const float* __restrict__ br, float* __restrict__ tkp,
                              int* __restrict__ tki) {
  int bt = (blockIdx.x << 2) | (threadIdx.x >> 6);  // token index b*T+t
  int lane = threadIdx.x & 63;
  const float* xr = x + (size_t)bt * C_;
  double acc[E_];
#pragma unroll
  for (int e = 0; e < E_; e++) acc[e] = 0.0;
#pragma unroll
  for (int i = 0; i < C_ / 64; i++) {
    int c = lane + i * 64;
    float xv = xr[c];
    const float* w = wr + c * E_;
#pragma unroll
    for (int e = 0; e < E_; e++) acc[e] += (double)xv * (double)w[e];
  }
#pragma unroll
  for (int off = 32; off > 0; off >>= 1) {
#pragma unroll
    for (int e = 0; e < E_; e++) acc[e] += __shfl_xor(acc[e], off);
  }
  if (lane == 0) {
    double lg[E_];
#pragma unroll
    for (int e = 0; e < E_; e++) lg[e] = acc[e] + (double)br[e];
    int i0 = 0;
#pragma unroll
    for (int e = 1; e < E_; e++) if (lg[e] > lg[i0]) i0 = e;
    int i1 = (i0 == 0) ? 1 : 0;
#pragma unroll
    for (int e = 0; e < E_; e++) if (e != i0 && lg[e] > lg[i1]) i1 = e;
    double mx = lg[i0], s = 0.0, pv[E_];
#pragma unroll
    for (int e = 0; e < E_; e++) { pv[e] = exp(lg[e] - mx); s += pv[e]; }
    tkp[bt * 2 + 0] = (float)(pv[i0] / s);
    tkp[bt * 2 + 1] = (float)(pv[i1] / s);
    tki[bt * 2 + 0] = i0;
    tki[bt * 2 + 1] = i1;
  }
}

// ---------- slot positions: parallel 8-way counted scan, one block per b ----------
// slot(i) = #same-expert entries before i in k-major order. 256 thr x 16 entries.
__global__ void pos_kernel(const int* __restrict__ tki, int* __restrict__ pos) {
  __shared__ int sc[256][9];  // +1 pad: avoid 8-way bank conflict
  int b = blockIdx.x;
  int tid = threadIdx.x;
  const int* tib = tki + (size_t)b * T_ * 2;
  int* pb = pos + (size_t)b * T_ * 2;
  int ids[16];
  int cnt[E_];
#pragma unroll
  for (int e = 0; e < E_; e++) cnt[e] = 0;
#pragma unroll
  for (int j = 0; j < 16; j++) {
    int i = tid * 16 + j;
    int k = i >> 11, t = i & (T_ - 1);  // k-major
    int id = tib[t * 2 + k];
    ids[j] = id;
#pragma unroll
    for (int e = 0; e < E_; e++) cnt[e] += (id == e);
  }
#pragma unroll
  for (int e = 0; e < E_; e++) sc[tid][e] = cnt[e];
  __syncthreads();
  // Hillis-Steele inclusive scan over 256 threads
  for (int off = 1; off < 256; off <<= 1) {
    int v[E_];
    if (tid >= off) {
#pragma unroll
      for (int e = 0; e < E_; e++) v[e] = sc[tid - off][e];
    }
    __syncthreads();
    if (tid >= off) {
#pragma unroll
      for (int e = 0; e < E_; e++) sc[tid][e] += v[e];
    }
    __syncthreads();
  }
  int base[E_];
#pragma unroll
  for (int e = 0; e < E_; e++) base[e] = (tid > 0) ? sc[tid - 1][e] : 0;
#pragma unroll
  for (int j = 0; j < 16; j++) {
    int i = tid * 16 + j;
    int k = i >> 11, t = i & (T_ - 1);
    int id = ids[j];
    int p = 0;
#pragma unroll
    for (int e = 0; e < E_; e++) p += (id == e) ? base[e] : 0;
    pb[t * 2 + k] = p;
#pragma unroll
    for (int e = 0; e < E_; e++) base[e] += (id == e);
  }
}

// ---------- dispatch: x row -> bf16 expert buffer [E][M_][C_] ----------
__global__ void dispatch_kernel(const float* __restrict__ x, const int* __restrict__ tki,
                                const int* __restrict__ pos, u16* __restrict__ Xd) {
  int gw = (blockIdx.x << 2) | (threadIdx.x >> 6);  // (b*T+t)*2 + k
  int lane = threadIdx.x & 63;
  int bt = gw >> 1;
  int b = bt >> 11;
  int e = tki[gw];
  int p = pos[gw];
  if (p >= CAP_) return;  // capacity drop
  const f32x4* src = (const f32x4*)(x + (size_t)bt * C_);
  u16* dst = Xd + ((size_t)e * M_ + (size_t)b * CAP_ + p) * C_;
#pragma unroll
  for (int i = 0; i < 3; i++) {
    f32x4 v = src[lane + i * 64];
    u16x4 o;
    o.x = f2bf(v.x); o.y = f2bf(v.y); o.z = f2bf(v.z); o.w = f2bf(v.w);
    *(u16x4*)(dst + (size_t)(lane + i * 64) * 4) = o;
  }
}

// ---------- GEMM1: S = silu((X@Wfc+bfc)*(X@Wg+bg)), dual-B 128x128 tile ----------
__global__ __launch_bounds__(256, 2) void gemm_fc_gate(
    const u16* __restrict__ Xd, const u16* __restrict__ WfcT, const u16* __restrict__ WgT,
    const float* __restrict__ bfc, const float* __restrict__ bg, u16* __restrict__ S,
    int e_base) {
  __shared__ __align__(16) u16 Alds[128 * 32];
  __shared__ __align__(16) u16 B1lds[128 * 32];
  __shared__ __align__(16) u16 B2lds[128 * 32];
  int bid = blockIdx.x;
  int e = e_base + bid / (40 * 24);
  int t = bid % (40 * 24);
  int tm = t / 24, tn = t % 24;
  int tid = threadIdx.x;
  int lane = tid & 63, wv = tid >> 6;
  int wm = wv & 1, wn = wv >> 1;
  int lr = lane & 15, quad = lane >> 4;

  const u16* XdE = Xd + (size_t)e * M_ * C_;
  const u16* B1E = WfcT + (size_t)e * H_ * C_;  // [H][C] = [N][K]
  const u16* B2E = WgT + (size_t)e * H_ * C_;

  int rhalf = tid >> 2;  // 0..63
  int chunk = tid & 3;
  const u16* gA0 = XdE + (size_t)(tm * 128 + rhalf) * C_ + chunk * 8;
  const u16* gA1 = gA0 + 64 * C_;
  const u16* gB10 = B1E + (size_t)(tn * 128 + rhalf) * C_ + chunk * 8;
  const u16* gB11 = gB10 + 64 * C_;
  const u16* gB20 = B2E + (size_t)(tn * 128 + rhalf) * C_ + chunk * 8;
  const u16* gB21 = gB20 + 64 * C_;
  u16* lA0 = Alds + (wv * 16) * 32;
  u16* lA1 = Alds + (64 + wv * 16) * 32;
  u16* lB10 = B1lds + (wv * 16) * 32;
  u16* lB11 = B1lds + (64 + wv * 16) * 32;
  u16* lB20 = B2lds + (wv * 16) * 32;
  u16* lB21 = B2lds + (64 + wv * 16) * 32;

  f32x4 acc1[4][4], acc2[4][4];
#pragma unroll
  for (int i = 0; i < 4; i++)
#pragma unroll
    for (int j = 0; j < 4; j++) {
      acc1[i][j] = (f32x4){0.f, 0.f, 0.f, 0.f};
      acc2[i][j] = (f32x4){0.f, 0.f, 0.f, 0.f};
    }

  for (int kt = 0; kt < C_ / 32; kt++) {
    int ko = kt * 32;
    __syncthreads();
    gl_lds16(gA0 + ko, lA0);
    gl_lds16(gA1 + ko, lA1);
    gl_lds16(gB10 + ko, lB10);
    gl_lds16(gB11 + ko, lB11);
    gl_lds16(gB20 + ko, lB20);
    gl_lds16(gB21 + ko, lB21);
    __syncthreads();
    bf16x8 af[4], b1f[4], b2f[4];
#pragma unroll
    for (int i = 0; i < 4; i++) {
      af[i] = ldfrag(Alds + (wm * 64 + i * 16 + lr) * 32 + quad * 8);
      b1f[i] = ldfrag(B1lds + (wn * 64 + i * 16 + lr) * 32 + quad * 8);
      b2f[i] = ldfrag(B2lds + (wn * 64 + i * 16 + lr) * 32 + quad * 8);
    }
#pragma unroll
    for (int i = 0; i < 4; i++)
#pragma unroll
      for (int j = 0; j < 4; j++) {
        acc1[i][j] = __builtin_amdgcn_mfma_f32_16x16x32_bf16(af[i], b1f[j], acc1[i][j], 0, 0, 0);
        acc2[i][j] = __builtin_amdgcn_mfma_f32_16x16x32_bf16(af[i], b2f[j], acc2[i][j], 0, 0, 0);
      }
  }

  u16* Se = S + (size_t)(e - e_base) * M_ * H_;
  const float* bfcE = bfc + (size_t)e * H_;
  const float* bgE = bg + (size_t)e * H_;
  int col0 = tn * 128 + wn * 64 + lr;
  int row0 = tm * 128 + wm * 64 + quad * 4;
#pragma unroll
  for (int j = 0; j < 4; j++) {
    int col = col0 + j * 16;
    float bf_ = bfcE[col], bg_ = bgE[col];
#pragma unroll
    for (int i = 0; i < 4; i++) {
      int row = row0 + i * 16;
#pragma unroll
      for (int r = 0; r < 4; r++) {
        float h = acc1[i][j][r] + bf_;
        float g = acc2[i][j][r] + bg_;
        float z = h * g;
        float sv = z / (1.f + __expf(-z));  // silu
        Se[(size_t)(row + r) * H_ + col] = f2bf(sv);
      }
    }
  }
}

// ---------- GEMM2: O = S @ Wproj + bproj ----------
__global__ __launch_bounds__(256, 2) void gemm_proj(
    const u16* __restrict__ S, const u16* __restrict__ WpT, const float* __restrict__ bp,
    u16* __restrict__ O, int e_base) {
  __shared__ __align__(16) u16 Alds[128 * 32];
  __shared__ __align__(16) u16 Blds[128 * 32];
  int bid = blockIdx.x;
  int eg = bid / (40 * 6);
  int e = e_base + eg;
  int t = bid % (40 * 6);
  int tm = t / 6, tn = t % 6;
  int tid = threadIdx.x;
  int lane = tid & 63, wv = tid >> 6;
  int wm = wv & 1, wn = wv >> 1;
  int lr = lane & 15, quad = lane >> 4;

  const u16* SE = S + (size_t)eg * M_ * H_;
  const u16* BE = WpT + (size_t)e * C_ * H_;  // [C][H] = [N][K]

  int rhalf = tid >> 2;
  int chunk = tid & 3;
  const u16* gA0 = SE + (size_t)(tm * 128 + rhalf) * H_ + chunk * 8;
  const u16* gA1 = gA0 + 64 * H_;
  const u16* gB0 = BE + (size_t)(tn * 128 + rhalf) * H_ + chunk * 8;
  const u16* gB1 = gB0 + 64 * H_;
  u16* lA0 = Alds + (wv * 16) * 32;
  u16* lA1 = Alds + (64 + wv * 16) * 32;
  u16* lB0 = Blds + (wv * 16) * 32;
  u16* lB1 = Blds + (64 + wv * 16) * 32;

  f32x4 acc[4][4];
#pragma unroll
  for (int i = 0; i < 4; i++)
#pragma unroll
    for (int j = 0; j < 4; j++) acc[i][j] = (f32x4){0.f, 0.f, 0.f, 0.f};

  for (int kt = 0; kt < H_ / 32; kt++) {
    int ko = kt * 32;
    __syncthreads();
    gl_lds16(gA0 + ko, lA0);
    gl_lds16(gA1 + ko, lA1);
    gl_lds16(gB0 + ko, lB0);
    gl_lds16(gB1 + ko, lB1);
    __syncthreads();
    bf16x8 af[4], bf[4];
#pragma unroll
    for (int i = 0; i < 4; i++) {
      af[i] = ldfrag(Alds + (wm * 64 + i * 16 + lr) * 32 + quad * 8);
      bf[i] = ldfrag(Blds + (wn * 64 + i * 16 + lr) * 32 + quad * 8);
    }
#pragma unroll
    for (int i = 0; i < 4; i++)
#pragma unroll
      for (int j = 0; j < 4; j++)
        acc[i][j] = __builtin_amdgcn_mfma_f32_16x16x32_bf16(af[i], bf[j], acc[i][j], 0, 0, 0);
  }

  u16* Oe = O + (size_t)e * M_ * C_;
  const float* bpE = bp + (size_t)e * C_;
  int col0 = tn * 128 + wn * 64 + lr;
  int row0 = tm * 128 + wm * 64 + quad * 4;
#pragma unroll
  for (int j = 0; j < 4; j++) {
    int col = col0 + j * 16;
    float bb = bpE[col];
#pragma unroll
    for (int i = 0; i < 4; i++) {
      int row = row0 + i * 16;
#pragma unroll
      for (int r = 0; r < 4; r++)
        Oe[(size_t)(row + r) * C_ + col] = f2bf(acc[i][j][r] + bb);
    }
  }
}

// ---------- combine: out = p0*O[e0,slot0] + p1*O[e1,slot1]  (clamp slot, jax gather) ----------
__global__ void combine_kernel(const u16* __restrict__ O, const float* __restrict__ tkp,
                               const int* __restrict__ tki, const int* __restrict__ pos,
                               float* __restrict__ out) {
  int bt = (blockIdx.x << 2) | (threadIdx.x >> 6);
  int lane = threadIdx.x & 63;
  int b = bt >> 11;
  int e0 = tki[bt * 2], e1 = tki[bt * 2 + 1];
  int p0 = pos[bt * 2], p1 = pos[bt * 2 + 1];
  p0 = p0 < CAP_ ? p0 : CAP_ - 1;  // jax clip-gather semantics
  p1 = p1 < CAP_ ? p1 : CAP_ - 1;
  float w0 = tkp[bt * 2], w1 = tkp[bt * 2 + 1];
  const u16* r0 = O + ((size_t)e0 * M_ + (size_t)b * CAP_ + p0) * C_;
  const u16* r1 = O + ((size_t)e1 * M_ + (size_t)b * CAP_ + p1) * C_;
  float* orow = out + (size_t)bt * C_;
#pragma unroll
  for (int i = 0; i < 3; i++) {
    int c = (lane + i * 64) * 4;
    u16x4 a0 = *(const u16x4*)(r0 + c);
    u16x4 a1 = *(const u16x4*)(r1 + c);
    f32x4 v;
    v.x = w0 * bf2f(a0.x) + w1 * bf2f(a1.x);
    v.y = w0 * bf2f(a0.y) + w1 * bf2f(a1.y);
    v.z = w0 * bf2f(a0.z) + w1 * bf2f(a1.z);
    v.w = w0 * bf2f(a0.w) + w1 * bf2f(a1.w);
    *(f32x4*)(orow + c) = v;
  }
}

extern "C" void kernel_launch(void* const* d_in, const int* in_sizes, int n_in,
                              void* d_out, int out_size, void* d_ws, size_t ws_size,
                              hipStream_t stream) {
  (void)in_sizes; (void)n_in; (void)out_size;
  const float* x = (const float*)d_in[0];
  const float* w_router = (const float*)d_in[1];
  const float* b_router = (const float*)d_in[2];
  const float* w_c_fc = (const float*)d_in[3];
  const float* b_c_fc = (const float*)d_in[4];
  const float* w_gate = (const float*)d_in[5];
  const float* b_gate = (const float*)d_in[6];
  const float* w_c_proj = (const float*)d_in[7];
  const float* b_c_proj = (const float*)d_in[8];
  float* out = (float*)d_out;

  char* p = (char*)d_ws;
  auto alloc = [&](size_t n) { char* r = p; p += (n + 255) & ~(size_t)255; return r; };
  const size_t WN = (size_t)E_ * C_ * H_;
  u16* WfcT = (u16*)alloc(WN * 2);
  u16* WgT = (u16*)alloc(WN * 2);
  u16* WpT = (u16*)alloc(WN * 2);
  u16* Xd = (u16*)alloc((size_t)E_ * M_ * C_ * 2);
  u16* O = (u16*)alloc((size_t)E_ * M_ * C_ * 2);
  float* tkp = (float*)alloc((size_t)B_ * T_ * 2 * 4);
  int* tki = (int*)alloc((size_t)B_ * T_ * 2 * 4);
  int* pos = (int*)alloc((size_t)B_ * T_ * 2 * 4);
  size_t fixed = (size_t)(p - (char*)d_ws);
  const size_t sbytes = (size_t)M_ * H_ * 2;  // per-expert S (31.5 MB)
  int g = 1;
  if (ws_size >= fixed + 8 * sbytes) g = 8;
  else if (ws_size >= fixed + 4 * sbytes) g = 4;
  else if (ws_size >= fixed + 2 * sbytes) g = 2;
  u16* S = (u16*)alloc((size_t)g * sbytes);

  dim3 blk(256);
  // weights -> bf16, transposed to [N][K]
  wconv_transpose<<<dim3(H_ / 32, C_ / 32, E_), blk, 0, stream>>>(w_c_fc, WfcT, C_, H_);
  wconv_transpose<<<dim3(H_ / 32, C_ / 32, E_), blk, 0, stream>>>(w_gate, WgT, C_, H_);
  wconv_transpose<<<dim3(C_ / 32, H_ / 32, E_), blk, 0, stream>>>(w_c_proj, WpT, H_, C_);

  router_kernel<<<dim3(B_ * T_ / 4), blk, 0, stream>>>(x, w_router, b_router, tkp, tki);
  pos_kernel<<<dim3(B_), blk, 0, stream>>>(tki, pos);
  dispatch_kernel<<<dim3(B_ * T_ * K_ / 4), blk, 0, stream>>>(x, tki, pos, Xd);

  for (int e0 = 0; e0 < E_; e0 += g) {
    gemm_fc_gate<<<dim3(g * 40 * 24), blk, 0, stream>>>(Xd, WfcT, WgT, b_c_fc, b_gate, S, e0);
    gemm_proj<<<dim3(g * 40 * 6), blk, 0, stream>>>(S, WpT, b_c_proj, O, e0);
  }

  combine_kernel<<<dim3(B_ * T_ / 4), blk, 0, stream>>>(O, tkp, tki, pos, out);
}